// Round 12
// baseline (6836.508 us; speedup 1.0000x reference)
//
#include <hip/hip_runtime.h>
#include <math.h>

#define DD 512
#define RB 16   // batch rows per block

typedef _Float16 half8v __attribute__((ext_vector_type(8)));
typedef __attribute__((ext_vector_type(4))) float f32x4;

__device__ __forceinline__ float sigm(float x) { return 1.0f / (1.0f + expf(-x)); }

// ---------- setup kernels ----------
__global__ void msd_gi_kernel(const float* __restrict__ emb,
                              const float* __restrict__ wf, const float* __restrict__ bf,
                              const float* __restrict__ ws_, const float* __restrict__ bs,
                              float* __restrict__ gif, float* __restrict__ gis)
{
    int t = blockIdx.x;
    int part = blockIdx.y;
    int net = part / 6;
    int j = (part % 6) * 256 + threadIdx.x;
    __shared__ float e[DD];
    for (int k = threadIdx.x; k < DD; k += 256) e[k] = emb[t * DD + k];
    __syncthreads();
    const float* w = net ? ws_ : wf;
    const float* b = net ? bs : bf;
    const float* wr = w + (size_t)j * DD;
    float acc = b[j];
    #pragma unroll 8
    for (int k = 0; k < DD; k += 4) {
        float4 wv = *reinterpret_cast<const float4*>(wr + k);
        acc = fmaf(wv.x, e[k], acc);
        acc = fmaf(wv.y, e[k + 1], acc);
        acc = fmaf(wv.z, e[k + 2], acc);
        acc = fmaf(wv.w, e[k + 3], acc);
    }
    (net ? gis : gif)[t * 1536 + j] = acc;
}

__global__ void msd_f2h_kernel(const float* __restrict__ in, _Float16* __restrict__ out, int n4)
{
    int i = blockIdx.x * 256 + threadIdx.x;
    if (i >= n4) return;
    float4 v = reinterpret_cast<const float4*>(in)[i];
    _Float16 o[4] = {(_Float16)v.x, (_Float16)v.y, (_Float16)v.z, (_Float16)v.w};
    *reinterpret_cast<ushort4*>(out + (size_t)i * 4) = *reinterpret_cast<ushort4*>(o);
}

__global__ void msd_init_kernel(const float* __restrict__ z, float* __restrict__ zf32,
                                float* __restrict__ zs32, _Float16* __restrict__ zf16,
                                _Float16* __restrict__ zs16, int n)
{
    int i = blockIdx.x * 256 + threadIdx.x;
    if (i < n) {
        float v = z[i];
        zf32[i] = v; zs32[i] = v;
        _Float16 h = (_Float16)v;
        zf16[i] = h; zs16[i] = h;
    }
}

// ---------- one full step, one dispatch ----------
// 128 blocks x 512 thr (8 waves). Block owns rows [16*bid, 16*bid+16) through
// all phases; only __syncthreads() between phases. Slow-GRU writeback is
// DEFERRED to after a barrier (all waves' A-fragment reads of zs16g complete
// before any wave overwrites it — the R11 race fix, same pattern as R5).
__global__ __launch_bounds__(512) void k_step(
    _Float16* __restrict__ zf16g, float* __restrict__ zf32g,
    _Float16* __restrict__ zs16g, float* __restrict__ zs32g,
    const _Float16* __restrict__ wfh, const _Float16* __restrict__ wsh,
    const _Float16* __restrict__ gwh,
    const float* __restrict__ bhhF, const float* __restrict__ bhhS,
    const float* __restrict__ giF, const float* __restrict__ giS,
    const float* __restrict__ gb, const float* __restrict__ gamma,
    const float* __restrict__ beta,
    float* __restrict__ out, int T, int t, int upd)
{
    __shared__ _Float16 sZfn[RB][520];    // fast GRU out (fp16), gate A + fuse
    __shared__ _Float16 sZs16[RB][520];   // slow state fp16 (gate A)
    __shared__ float    sZs32[RB][516];   // slow state fp32 (fuse)
    __shared__ float    sGlog[RB][516];   // gate logits

    const int tid = threadIdx.x;
    const int l = tid & 63, w = tid >> 6;
    const int lr = l & 15, hi = l >> 4;
    const int koff = hi * 8, er4 = hi * 4;
    const int r0 = blockIdx.x * RB;

    // ================= fast GRU (wave w -> cols [64w, 64w+64) x 3 gates) ====
    {
        half8v a[16];
        const _Float16* pA = zf16g + (size_t)(r0 + lr) * DD + koff;
        #pragma unroll
        for (int kt = 0; kt < 16; ++kt) a[kt] = *(const half8v*)(pA + kt * 32);

        #pragma unroll
        for (int cf = 0; cf < 4; ++cf) {
            const int c0 = w * 64 + cf * 16;
            const half8v* pR = (const half8v*)(wfh + (size_t)(c0 + lr) * DD + koff);
            const half8v* pZ = (const half8v*)(wfh + (size_t)(512 + c0 + lr) * DD + koff);
            const half8v* pN = (const half8v*)(wfh + (size_t)(1024 + c0 + lr) * DD + koff);
            f32x4 aR = {0.f,0.f,0.f,0.f}, aZ = {0.f,0.f,0.f,0.f}, aN = {0.f,0.f,0.f,0.f};
            #pragma unroll
            for (int kt = 0; kt < 16; ++kt) {
                aR = __builtin_amdgcn_mfma_f32_16x16x32_f16(a[kt], pR[kt*4], aR, 0,0,0);
                aZ = __builtin_amdgcn_mfma_f32_16x16x32_f16(a[kt], pZ[kt*4], aZ, 0,0,0);
                aN = __builtin_amdgcn_mfma_f32_16x16x32_f16(a[kt], pN[kt*4], aN, 0,0,0);
            }
            const int col = c0 + lr;
            const float gir = giF[col]        + bhhF[col];
            const float giz = giF[col + 512]  + bhhF[col + 512];
            const float gin = giF[col + 1024];
            const float bn  = bhhF[col + 1024];
            #pragma unroll
            for (int e = 0; e < 4; ++e) {
                const int rl = er4 + e;
                float r_ = sigm(gir + aR[e]);
                float zg = sigm(giz + aZ[e]);
                float nn = tanhf(gin + r_ * (aN[e] + bn));
                float hv = zf32g[(size_t)(r0 + rl) * DD + col];
                sZfn[rl][col] = (_Float16)((1.f - zg) * nn + zg * hv);
            }
        }
    }

    // ================= slow GRU compute (upd) -> registers ==================
    float oS[4][4];
    if (upd) {
        half8v a[16];
        const _Float16* pA = zs16g + (size_t)(r0 + lr) * DD + koff;
        #pragma unroll
        for (int kt = 0; kt < 16; ++kt) a[kt] = *(const half8v*)(pA + kt * 32);

        #pragma unroll
        for (int cf = 0; cf < 4; ++cf) {
            const int c0 = w * 64 + cf * 16;
            const half8v* pR = (const half8v*)(wsh + (size_t)(c0 + lr) * DD + koff);
            const half8v* pZ = (const half8v*)(wsh + (size_t)(512 + c0 + lr) * DD + koff);
            const half8v* pN = (const half8v*)(wsh + (size_t)(1024 + c0 + lr) * DD + koff);
            f32x4 aR = {0.f,0.f,0.f,0.f}, aZ = {0.f,0.f,0.f,0.f}, aN = {0.f,0.f,0.f,0.f};
            #pragma unroll
            for (int kt = 0; kt < 16; ++kt) {
                aR = __builtin_amdgcn_mfma_f32_16x16x32_f16(a[kt], pR[kt*4], aR, 0,0,0);
                aZ = __builtin_amdgcn_mfma_f32_16x16x32_f16(a[kt], pZ[kt*4], aZ, 0,0,0);
                aN = __builtin_amdgcn_mfma_f32_16x16x32_f16(a[kt], pN[kt*4], aN, 0,0,0);
            }
            const int col = c0 + lr;
            const float gir = giS[col]        + bhhS[col];
            const float giz = giS[col + 512]  + bhhS[col + 512];
            const float gin = giS[col + 1024];
            const float bn  = bhhS[col + 1024];
            #pragma unroll
            for (int e = 0; e < 4; ++e) {
                const int rl = er4 + e;
                float r_ = sigm(gir + aR[e]);
                float zg = sigm(giz + aZ[e]);
                float nn = tanhf(gin + r_ * (aN[e] + bn));
                float hv = zs32g[(size_t)(r0 + rl) * DD + col];
                oS[cf][e] = (1.f - zg) * nn + zg * hv;
            }
        }
    }
    __syncthreads();   // all zs16g A-reads done; sZfn complete

    // ================= slow writeback / LDS refresh =========================
    if (upd) {
        #pragma unroll
        for (int cf = 0; cf < 4; ++cf) {
            const int col = w * 64 + cf * 16 + lr;
            #pragma unroll
            for (int e = 0; e < 4; ++e) {
                const int rl = er4 + e;
                const float o = oS[cf][e];
                sZs16[rl][col] = (_Float16)o;
                sZs32[rl][col] = o;
                zs16g[(size_t)(r0 + rl) * DD + col] = (_Float16)o;
                zs32g[(size_t)(r0 + rl) * DD + col] = o;
            }
        }
    } else {
        for (int i = tid; i < RB * DD; i += 512) {
            const int r = i >> 9, c = i & (DD - 1);
            sZs16[r][c] = zs16g[(size_t)(r0 + r) * DD + c];
            sZs32[r][c] = zs32g[(size_t)(r0 + r) * DD + c];
        }
    }
    __syncthreads();

    // ================= gate GEMM (K=1024, A from LDS) =======================
    {
        half8v af[16], as2[16];
        #pragma unroll
        for (int kt = 0; kt < 16; ++kt) {
            af[kt]  = *(const half8v*)&sZfn[lr][kt * 32 + koff];
            as2[kt] = *(const half8v*)&sZs16[lr][kt * 32 + koff];
        }
        #pragma unroll
        for (int cf = 0; cf < 4; ++cf) {
            const int c0 = w * 64 + cf * 16;
            const half8v* pB = (const half8v*)(gwh + (size_t)(c0 + lr) * 1024 + koff);
            f32x4 acc = {0.f,0.f,0.f,0.f};
            #pragma unroll
            for (int kt = 0; kt < 16; ++kt)
                acc = __builtin_amdgcn_mfma_f32_16x16x32_f16(af[kt], pB[kt*4], acc, 0,0,0);
            #pragma unroll
            for (int kt = 0; kt < 16; ++kt)
                acc = __builtin_amdgcn_mfma_f32_16x16x32_f16(as2[kt], pB[64 + kt*4], acc, 0,0,0);
            const int col = c0 + lr;
            const float bias = gb[col];
            #pragma unroll
            for (int e = 0; e < 4; ++e)
                sGlog[er4 + e][col] = acc[e] + bias;
        }
    }
    __syncthreads();

    // ================= fuse + LayerNorm (2 rows per wave) ===================
    #pragma unroll
    for (int rr = 0; rr < 2; ++rr) {
        const int row = w * 2 + rr;
        const size_t grow = (size_t)(r0 + row) * DD;
        float p[8];
        float s = 0.f, s2 = 0.f;
        #pragma unroll
        for (int j = 0; j < 8; ++j) {
            const int c = l + j * 64;
            float g  = sigm(sGlog[row][c]);
            float pv = g * (float)sZfn[row][c] + (1.f - g) * sZs32[row][c] + zf32g[grow + c];
            p[j] = pv; s += pv; s2 += pv * pv;
        }
        #pragma unroll
        for (int off = 1; off < 64; off <<= 1) {
            s  += __shfl_xor(s, off);
            s2 += __shfl_xor(s2, off);
        }
        const float mu  = s * (1.0f / DD);
        const float inv = rsqrtf(s2 * (1.0f / DD) - mu * mu + 1e-5f);
        float* op = out + ((size_t)(r0 + row) * T + t) * DD;
        #pragma unroll
        for (int j = 0; j < 8; ++j) {
            const int c = l + j * 64;
            float o = (p[j] - mu) * inv * gamma[c] + beta[c];
            __builtin_nontemporal_store(o, op + c);   // keep L2 for weights
            zf32g[grow + c] = o;
            zf16g[grow + c] = (_Float16)o;
        }
    }
}

extern "C" void kernel_launch(void* const* d_in, const int* in_sizes, int n_in,
                              void* d_out, int out_size, void* d_ws, size_t ws_size,
                              hipStream_t stream)
{
    const float* z_init = (const float*)d_in[0];
    const float* emb    = (const float*)d_in[1];
    const float* f_wih  = (const float*)d_in[2];
    const float* f_whh  = (const float*)d_in[3];
    const float* f_bih  = (const float*)d_in[4];
    const float* f_bhh  = (const float*)d_in[5];
    const float* s_wih  = (const float*)d_in[6];
    const float* s_whh  = (const float*)d_in[7];
    const float* s_bih  = (const float*)d_in[8];
    const float* s_bhh  = (const float*)d_in[9];
    const float* gw     = (const float*)d_in[10];
    const float* gb     = (const float*)d_in[11];
    const float* gamma  = (const float*)d_in[12];
    const float* beta   = (const float*)d_in[13];

    const int B = in_sizes[0] / DD;          // 2048
    int T = out_size / in_sizes[0];          // 64
    float* out = (float*)d_out;

    char* p = (char*)d_ws;
    auto alloc = [&](size_t bytes) { char* q = p; p += (bytes + 255) & ~(size_t)255; return q; };

    float* gi_f = (float*)alloc((size_t)T * 1536 * 4);
    float* gi_s = (float*)alloc((size_t)T * 1536 * 4);
    _Float16* wfh = (_Float16*)alloc((size_t)1536 * DD * 2);
    _Float16* wsh = (_Float16*)alloc((size_t)1536 * DD * 2);
    _Float16* gwh = (_Float16*)alloc((size_t)DD * 1024 * 2);
    size_t bd4 = (size_t)B * DD * 4;
    size_t bd2 = (size_t)B * DD * 2;
    float* zf32 = (float*)alloc(bd4);
    float* zs32 = (float*)alloc(bd4);
    _Float16* zf16 = (_Float16*)alloc(bd2);
    _Float16* zs16 = (_Float16*)alloc(bd2);

    msd_gi_kernel<<<dim3(T, 12), 256, 0, stream>>>(emb, f_wih, f_bih, s_wih, s_bih, gi_f, gi_s);
    msd_f2h_kernel<<<(1536 * DD / 4 + 255) / 256, 256, 0, stream>>>(f_whh, wfh, 1536 * DD / 4);
    msd_f2h_kernel<<<(1536 * DD / 4 + 255) / 256, 256, 0, stream>>>(s_whh, wsh, 1536 * DD / 4);
    msd_f2h_kernel<<<(DD * 1024 / 4 + 255) / 256, 256, 0, stream>>>(gw, gwh, DD * 1024 / 4);
    msd_init_kernel<<<(B * DD + 255) / 256, 256, 0, stream>>>(z_init, zf32, zs32, zf16, zs16, B * DD);

    for (int t = 0; t < T; ++t) {
        const int upd = ((t & 1) == 0) ? 1 : 0;
        k_step<<<B / RB, 512, 0, stream>>>(
            zf16, zf32, zs16, zs32, wfh, wsh, gwh, f_bhh, s_bhh,
            gi_f + (size_t)t * 1536, gi_s + (size_t)t * 1536,
            gb, gamma, beta, out, T, t, upd);
    }
}